// Round 10
// baseline (273.708 us; speedup 1.0000x reference)
//
#include <hip/hip_runtime.h>
#include <hip/hip_fp16.h>

// GCN: 4 layers, N=50000, E=800000, C: 128->96->96->96->96
// - bucket sort by dst: bin (LDS counting-sort of 4096-edge tiles -> coalesced
//   slab flush) + fine (per-bucket in-LDS sort) -> es(ushort), offs, dinv,
//   nodeord (degree-sorted -> degree-uniform waves).
// - mix_k: bin blocks + layer-1 MFMA GEMM blocks in one dispatch.
// - fused_k (x3): gather-aggregate 16 nodes (+bias, relu) -> 3KB LDS A-tile ->
//   MFMA with next layer's swizzled W -> row-major fp16 H.
// - aggf_k: final gather-aggregate + b4 -> fp32 out.
// - gather loop: pipelined chunks of 4 with TAIL PADDING (clamped index,
//   zero weight) -> no serial scalar tail; indices prefetched a chunk ahead.
// - dinv[src] loaded per edge (200KB, L2-hot; enorm precompute regressed r7).

#define NN 50000
#define NE 800000
#define K1 128
#define CH 96
#define NT 3125    // NN/16 row-tiles (exact)
#define NPB 196    // dst buckets of 256 nodes
#define BCAP 5120  // slab capacity per bucket (mean 4082, ~16 sigma headroom)
#define NSLOT (NPB * 256)  // 50176 nodeord slots
#define NBB 196    // bin blocks (4096 edges each; 196*4096 >= NE)
#define E4 4096

typedef _Float16 v8h __attribute__((ext_vector_type(8)));
typedef _Float16 v4h __attribute__((ext_vector_type(4)));
typedef float f4 __attribute__((ext_vector_type(4)));
typedef unsigned short ushort_t;

static inline size_t al256(size_t x) { return (x + 255) & ~size_t(255); }

// ---------------- weight swizzle + bcnt zero ----------------
__global__ __launch_bounds__(256) void wconv_k(const float* __restrict__ W1f,
                                               const float* __restrict__ W2f,
                                               const float* __restrict__ W3f,
                                               const float* __restrict__ W4f,
                                               _Float16* __restrict__ W1sw,
                                               _Float16* __restrict__ W2sw,
                                               _Float16* __restrict__ W3sw,
                                               _Float16* __restrict__ W4sw,
                                               int* __restrict__ bcnt) {
    int id = blockIdx.x * 256 + threadIdx.x;
    if (id < NPB) bcnt[id] = 0;
    const float* W;
    _Float16* Wsw;
    int K, lid;
    if (id < 3072) {            // 96*32
        W = W1f; Wsw = W1sw; K = K1; lid = id;
    } else {
        int r = id - 3072;
        if (r >= 3 * 2304) return;
        int wsel = r / 2304;
        lid = r % 2304;         // 96*24
        K = CH;
        W = (wsel == 0) ? W2f : (wsel == 1) ? W3f : W4f;
        Wsw = (wsel == 0) ? W2sw : (wsel == 1) ? W3sw : W4sw;
    }
    int kc = K / 4;
    int n = lid / kc, k0 = (lid % kc) * 4;
    v4h o;
    o.x = (_Float16)W[(k0 + 0) * 96 + n];
    o.y = (_Float16)W[(k0 + 1) * 96 + n];
    o.z = (_Float16)W[(k0 + 2) * 96 + n];
    o.w = (_Float16)W[(k0 + 3) * 96 + n];
    int off = (n >> 4) * (16 * K) + (k0 >> 3) * 128 + (n & 15) * 8 + (k0 & 7);
    *(v4h*)&Wsw[off] = o;
}

// ---------------- mix: bin (blocks [0,NBB)) + layer-1 GEMM (rest) ------------
// bin: LDS counting-sort of a 4096-edge tile by bucket, then coalesced
// bucket-run flush into per-bucket slabs. word = src(16b) | ldst(8b)<<16.
__global__ __launch_bounds__(256) void mix_k(const int* __restrict__ src,
                                             const int* __restrict__ dst,
                                             int* __restrict__ bcnt,
                                             int* __restrict__ est,
                                             const float* __restrict__ Xf,
                                             const _Float16* __restrict__ Wsw,
                                             _Float16* __restrict__ Hh) {
    __shared__ int smem_i[7424];  // 29KB: bin staging; gemm uses 16KB as fp16
    int tid = threadIdx.x;

    if (blockIdx.x < NBB) {
        int* lwv = smem_i;                      // 4096
        ushort_t* lbk = (ushort_t*)(smem_i + 4096);  // 4096 ushort (2048 ints)
        int* h2 = smem_i + 4096 + 2048;         // 256
        int* bst = h2 + 256;                    // 256
        int* basel = bst + 256;                 // 256
        if (tid < 256) h2[tid] = 0;
        __syncthreads();
        int base = blockIdx.x * E4;
        int cntb = NE - base;
        if (cntb > E4) cntb = E4;
        int wv[16], bk[16], rk[16];
#pragma unroll
        for (int k = 0; k < 16; k++) {
            int i = base + k * 256 + tid;
            bk[k] = -1;
            if (i < NE) {
                int s = src[i], d = dst[i];
                bk[k] = d >> 8;
                wv[k] = s | ((d & 255) << 16);
                rk[k] = atomicAdd(&h2[bk[k]], 1);
            }
        }
        __syncthreads();
        // scan h2 -> bst (exclusive), reserve slab space
        {
            int hv = h2[tid];
            bst[tid] = hv;
            __syncthreads();
            for (int d = 1; d < 256; d <<= 1) {
                int t = (tid >= d) ? bst[tid - d] : 0;
                __syncthreads();
                bst[tid] += t;
                __syncthreads();
            }
            int excl = bst[tid] - hv;
            __syncthreads();
            bst[tid] = excl;
            if (tid < NPB && hv) basel[tid] = atomicAdd(&bcnt[tid], hv);
        }
        __syncthreads();
        // place into LDS sorted by bucket
#pragma unroll
        for (int k = 0; k < 16; k++) {
            if (bk[k] >= 0) {
                int slot = bst[bk[k]] + rk[k];
                lwv[slot] = wv[k];
                lbk[slot] = (ushort_t)bk[k];
            }
        }
        __syncthreads();
        // coalesced flush: consecutive slots in a bucket -> consecutive est
        for (int j = tid; j < cntb; j += 256) {
            int b = lbk[j];
            int pos = basel[b] + (j - bst[b]);
            est[b * BCAP + pos] = lwv[j];
        }
        return;
    }

    // ---- gemm1 path ----
    _Float16* smem = (_Float16*)smem_i;
    int bid = blockIdx.x - NBB;
    constexpr int K = K1;
    constexpr int KK = K / 32;
    int wave = tid >> 6;
    int lane = tid & 63;
    int l15 = lane & 15, quad = lane >> 4;
    int t = bid * 4 + wave;

    int row0 = bid * 64;
    for (int i = tid; i < 64 * (K / 4); i += 256) {
        int r = i / (K / 4), c = i % (K / 4);
        int gr = row0 + r;
        float4 v = make_float4(0.f, 0.f, 0.f, 0.f);
        if (gr < NN) v = *(const float4*)&Xf[(size_t)gr * K + c * 4];
        int k0 = c * 4;
        v4h h;
        h.x = (_Float16)v.x; h.y = (_Float16)v.y;
        h.z = (_Float16)v.z; h.w = (_Float16)v.w;
        int off = (r >> 4) * (16 * K) + (k0 >> 3) * 128 + (r & 15) * 8 + (k0 & 7);
        *(v4h*)&smem[off] = h;
    }
    __syncthreads();

    v8h a[KK];
#pragma unroll
    for (int kk = 0; kk < KK; kk++) {
        int off = wave * (16 * K) + (kk * 4 + quad) * 128 + l15 * 8;
        a[kk] = *(v8h*)&smem[off];
    }

    f4 acc[6];
#pragma unroll
    for (int cb = 0; cb < 6; cb++) acc[cb] = {0.f, 0.f, 0.f, 0.f};

#pragma unroll
    for (int kk = 0; kk < KK; kk++) {
        v8h b[6];
#pragma unroll
        for (int cb = 0; cb < 6; cb++)
            b[cb] = ((const v8h*)Wsw)[cb * (2 * K) + (kk * 4 + quad) * 16 + l15];
#pragma unroll
        for (int cb = 0; cb < 6; cb++)
            acc[cb] = __builtin_amdgcn_mfma_f32_16x16x32_f16(b[cb], a[kk], acc[cb], 0, 0, 0);
    }

    if (t < NT) {
        int row = t * 16 + l15;
#pragma unroll
        for (int cb = 0; cb < 6; cb++) {
            v4h o;
            o.x = (_Float16)acc[cb].x;
            o.y = (_Float16)acc[cb].y;
            o.z = (_Float16)acc[cb].z;
            o.w = (_Float16)acc[cb].w;
            *(v4h*)&Hh[(size_t)row * 96 + cb * 16 + quad * 4] = o;
        }
    }
}

// ---------------- per-bucket sort (1024 thr); emit es/offs/dinv/nodeord ------
__global__ __launch_bounds__(1024) void fine_k(const int* __restrict__ est,
                                               const int* __restrict__ bcnt,
                                               ushort_t* __restrict__ es,
                                               int* __restrict__ offs,
                                               float* __restrict__ dinv,
                                               int* __restrict__ nodeord) {
    __shared__ ushort_t lsrc[BCAP];
    __shared__ unsigned char ldst[BCAP];
    __shared__ ushort_t lout[BCAP];
    __shared__ int sc[256];
    __shared__ int hist[256];
    __shared__ int cur[256];
    __shared__ int dh[256];

    int b = blockIdx.x;
    int tid = threadIdx.x;
    bool lead = tid < 256;

    // global bucket prefix: scan bcnt[0..NPB)
    if (lead) sc[tid] = (tid < NPB) ? bcnt[tid] : 0;
    __syncthreads();
    for (int d = 1; d < 256; d <<= 1) {
        int t = 0;
        if (lead && tid >= d) t = sc[tid - d];
        __syncthreads();
        if (lead) sc[tid] += t;
        __syncthreads();
    }
    int cnt = bcnt[b];
    if (cnt > BCAP) cnt = BCAP;
    int base = sc[b] - cnt;  // exclusive prefix for this bucket

    if (lead) hist[tid] = 0;
    __syncthreads();
    for (int j = tid; j < cnt; j += 1024) {
        int w = est[b * BCAP + j];
        lsrc[j] = (ushort_t)(w & 0xFFFF);
        int l = (w >> 16) & 255;
        ldst[j] = (unsigned char)l;
        atomicAdd(&hist[l], 1);
    }
    __syncthreads();
    int hv = lead ? hist[tid] : 0;
    if (lead) sc[tid] = hv;
    __syncthreads();
    for (int d = 1; d < 256; d <<= 1) {
        int t = 0;
        if (lead && tid >= d) t = sc[tid - d];
        __syncthreads();
        if (lead) sc[tid] += t;
        __syncthreads();
    }
    int nvalid = NN - (b << 8);
    if (nvalid > 256) nvalid = 256;
    if (lead) {
        int excl = sc[tid] - hv;
        int n = (b << 8) + tid;
        if (tid < nvalid) {
            offs[n] = base + excl;
            dinv[n] = rsqrtf(1.0f + (float)hv);
        }
        if (n == NN) offs[NN] = base + excl;  // == NE (last bucket)
        cur[tid] = excl;
        dh[tid] = 0;
    }
    __syncthreads();
    for (int j = tid; j < cnt; j += 1024) {
        int r = atomicAdd(&cur[ldst[j]], 1);
        lout[r] = lsrc[j];
    }
    if (lead) {
        int dv = (hv > 255) ? 255 : hv;
        if (tid < nvalid) atomicAdd(&dh[dv], 1);
    }
    __syncthreads();
    for (int j = tid; j < cnt; j += 1024) es[base + j] = lout[j];
    // degree-rank counting sort -> nodeord
    int dhv = lead ? dh[tid] : 0;
    if (lead) sc[tid] = dhv;
    __syncthreads();
    for (int d = 1; d < 256; d <<= 1) {
        int t = 0;
        if (lead && tid >= d) t = sc[tid - d];
        __syncthreads();
        if (lead) sc[tid] += t;
        __syncthreads();
    }
    if (lead) cur[tid] = sc[tid] - dhv;
    __syncthreads();
    if (lead) {
        int dv = (hv > 255) ? 255 : hv;
        if (tid < nvalid) {
            int slot = atomicAdd(&cur[dv], 1);
            nodeord[b * 256 + slot] = (b << 8) + tid;
        } else {
            nodeord[b * 256 + tid] = b << 8;  // safe duplicate
        }
    }
}

// ---------------- shared gather-accumulate helper ----------------
__device__ __forceinline__ void acc8(v8h h, float w, float* a) {
    a[0] = fmaf(w, (float)h.s0, a[0]);
    a[1] = fmaf(w, (float)h.s1, a[1]);
    a[2] = fmaf(w, (float)h.s2, a[2]);
    a[3] = fmaf(w, (float)h.s3, a[3]);
    a[4] = fmaf(w, (float)h.s4, a[4]);
    a[5] = fmaf(w, (float)h.s5, a[5]);
    a[6] = fmaf(w, (float)h.s6, a[6]);
    a[7] = fmaf(w, (float)h.s7, a[7]);
}

// Pipelined gather, chunk=4, TAIL-PADDED: indices clamped to e1-1, pad weight
// 0 -> every edge flows through the pipeline; no serial scalar tail.
__device__ __forceinline__ void gather_node(const _Float16* __restrict__ Hh,
                                            const int* __restrict__ offs,
                                            const ushort_t* __restrict__ es,
                                            const float* __restrict__ dinv,
                                            const float* __restrict__ bias,
                                            int n, int c8, float* a) {
    const _Float16* Hc = Hh + c8 * 8;
    float di = dinv[n];
    int e0 = offs[n], e1 = offs[n + 1];
    // self-loop row: issue first, in flight for the whole loop
    v8h hs = *(const v8h*)&Hc[(size_t)n * 96];
    int deg = e1 - e0;
    int nch = (deg + 3) >> 2;
    if (nch >= 2) {
        int s0[4], s1[4], sn[4];
        float w0[4], w1[4];
        v8h h0[4], h1[4];
#pragma unroll
        for (int j = 0; j < 4; j++) {
            int e = e0 + j;
            s0[j] = es[e < e1 ? e : e1 - 1];
        }
#pragma unroll
        for (int j = 0; j < 4; j++) h0[j] = *(const v8h*)&Hc[(size_t)s0[j] * 96];
#pragma unroll
        for (int j = 0; j < 4; j++)
            w0[j] = (e0 + j < e1) ? dinv[s0[j]] * di : 0.f;
#pragma unroll
        for (int j = 0; j < 4; j++) {
            int e = e0 + 4 + j;
            s1[j] = es[e < e1 ? e : e1 - 1];
        }
        for (int c = 1; c < nch; c++) {
            int eb = e0 + (c << 2);
            // rows for chunk c — indices loaded an iteration ago: no idx wait
#pragma unroll
            for (int j = 0; j < 4; j++) h1[j] = *(const v8h*)&Hc[(size_t)s1[j] * 96];
#pragma unroll
            for (int j = 0; j < 4; j++)
                w1[j] = (eb + j < e1) ? dinv[s1[j]] * di : 0.f;
            // indices for chunk c+1 (in flight during consume below)
            if (c + 1 < nch) {
                int eidx = e0 + ((c + 1) << 2);
#pragma unroll
                for (int j = 0; j < 4; j++) {
                    int e = eidx + j;
                    sn[j] = es[e < e1 ? e : e1 - 1];
                }
            }
            // consume chunk c-1 while chunk-c rows are in flight
#pragma unroll
            for (int j = 0; j < 4; j++) acc8(h0[j], w0[j], a);
#pragma unroll
            for (int j = 0; j < 4; j++) {
                h0[j] = h1[j];
                w0[j] = w1[j];
                s1[j] = sn[j];
            }
        }
#pragma unroll
        for (int j = 0; j < 4; j++) acc8(h0[j], w0[j], a);
    } else if (nch == 1) {
        int s0[4];
        float w0[4];
        v8h h0[4];
#pragma unroll
        for (int j = 0; j < 4; j++) {
            int e = e0 + j;
            s0[j] = es[e < e1 ? e : e1 - 1];
        }
#pragma unroll
        for (int j = 0; j < 4; j++) h0[j] = *(const v8h*)&Hc[(size_t)s0[j] * 96];
#pragma unroll
        for (int j = 0; j < 4; j++)
            w0[j] = (e0 + j < e1) ? dinv[s0[j]] * di : 0.f;
#pragma unroll
        for (int j = 0; j < 4; j++) acc8(h0[j], w0[j], a);
    }
    // self-loop + bias
    acc8(hs, di * di, a);
    float4 bv0 = *(const float4*)&bias[c8 * 8];
    float4 bv1 = *(const float4*)&bias[c8 * 8 + 4];
    a[0] += bv0.x; a[1] += bv0.y; a[2] += bv0.z; a[3] += bv0.w;
    a[4] += bv1.x; a[5] += bv1.y; a[6] += bv1.z; a[7] += bv1.w;
}

// ---------------- fused: F = relu(agg(Hprev)+bias); Hnext = F @ W ------------
__global__ __launch_bounds__(192) void fused_k(const _Float16* __restrict__ Hprev,
                                               const int* __restrict__ offs,
                                               const ushort_t* __restrict__ es,
                                               const float* __restrict__ dinv,
                                               const float* __restrict__ bias,
                                               const _Float16* __restrict__ Wsw,
                                               const int* __restrict__ nodeord,
                                               _Float16* __restrict__ Hnext) {
    __shared__ _Float16 atile[1536];  // 16 x 96 in MFMA-A swizzle
    int tid = threadIdx.x;
    int g = tid / 12, c8 = tid % 12;
    int n = nodeord[blockIdx.x * 16 + g];
    float a[8] = {0.f, 0.f, 0.f, 0.f, 0.f, 0.f, 0.f, 0.f};
    gather_node(Hprev, offs, es, dinv, bias, n, c8, a);
    v8h o;
    o.s0 = (_Float16)fmaxf(a[0], 0.f); o.s1 = (_Float16)fmaxf(a[1], 0.f);
    o.s2 = (_Float16)fmaxf(a[2], 0.f); o.s3 = (_Float16)fmaxf(a[3], 0.f);
    o.s4 = (_Float16)fmaxf(a[4], 0.f); o.s5 = (_Float16)fmaxf(a[5], 0.f);
    o.s6 = (_Float16)fmaxf(a[6], 0.f); o.s7 = (_Float16)fmaxf(a[7], 0.f);
    *(v8h*)&atile[c8 * 128 + g * 8] = o;
    __syncthreads();

    // MFMA phase: wave w handles col-blocks {2w, 2w+1}
    int wave = tid >> 6;
    int lane = tid & 63;
    int l15 = lane & 15, quad = lane >> 4;
    v8h af[3];
#pragma unroll
    for (int kk = 0; kk < 3; kk++)
        af[kk] = *(v8h*)&atile[(kk * 4 + quad) * 128 + l15 * 8];
    int nrow = nodeord[blockIdx.x * 16 + l15];
#pragma unroll
    for (int c = 0; c < 2; c++) {
        int cb = wave * 2 + c;
        f4 acc = {0.f, 0.f, 0.f, 0.f};
#pragma unroll
        for (int kk = 0; kk < 3; kk++) {
            v8h bf = ((const v8h*)Wsw)[cb * 192 + (kk * 4 + quad) * 16 + l15];
            acc = __builtin_amdgcn_mfma_f32_16x16x32_f16(bf, af[kk], acc, 0, 0, 0);
        }
        v4h o2;
        o2.x = (_Float16)acc.x; o2.y = (_Float16)acc.y;
        o2.z = (_Float16)acc.z; o2.w = (_Float16)acc.w;
        *(v4h*)&Hnext[(size_t)nrow * 96 + cb * 16 + quad * 4] = o2;
    }
}

// ---------------- final aggregation -> fp32 out ----------------
__global__ __launch_bounds__(192) void aggf_k(const _Float16* __restrict__ Hh,
                                              const int* __restrict__ offs,
                                              const ushort_t* __restrict__ es,
                                              const float* __restrict__ dinv,
                                              const float* __restrict__ bias,
                                              const int* __restrict__ nodeord,
                                              float* __restrict__ out) {
    int tid = threadIdx.x;
    int g = tid / 12, c8 = tid % 12;
    int n = nodeord[blockIdx.x * 16 + g];
    float a[8] = {0.f, 0.f, 0.f, 0.f, 0.f, 0.f, 0.f, 0.f};
    gather_node(Hh, offs, es, dinv, bias, n, c8, a);
    float4 o0 = {a[0], a[1], a[2], a[3]};
    float4 o1 = {a[4], a[5], a[6], a[7]};
    *(float4*)&out[(size_t)n * 96 + c8 * 8] = o0;
    *(float4*)&out[(size_t)n * 96 + c8 * 8 + 4] = o1;
}

// ---------------- launch ----------------

extern "C" void kernel_launch(void* const* d_in, const int* in_sizes, int n_in,
                              void* d_out, int out_size, void* d_ws, size_t ws_size,
                              hipStream_t stream) {
    const float* x = (const float*)d_in[0];
    const int* ei = (const int*)d_in[1];
    const float* W1 = (const float*)d_in[2];
    const float* b1 = (const float*)d_in[3];
    const float* W2 = (const float*)d_in[4];
    const float* b2 = (const float*)d_in[5];
    const float* W3 = (const float*)d_in[6];
    const float* b3 = (const float*)d_in[7];
    const float* W4 = (const float*)d_in[8];
    const float* b4 = (const float*)d_in[9];
    float* out = (float*)d_out;

    const int* src = ei;
    const int* dst = ei + NE;

    char* ws = (char*)d_ws;
    size_t o = 0;
    _Float16* Ha = (_Float16*)(ws + o);   o += al256((size_t)NN * 96 * 2);
    _Float16* Hb = (_Float16*)(ws + o);   o += al256((size_t)NN * 96 * 2);
    _Float16* W1sw = (_Float16*)(ws + o); o += al256((size_t)96 * K1 * 2);
    _Float16* W2sw = (_Float16*)(ws + o); o += al256((size_t)96 * 96 * 2);
    _Float16* W3sw = (_Float16*)(ws + o); o += al256((size_t)96 * 96 * 2);
    _Float16* W4sw = (_Float16*)(ws + o); o += al256((size_t)96 * 96 * 2);
    int* est = (int*)(ws + o);            o += al256((size_t)NPB * BCAP * 4);
    ushort_t* es = (ushort_t*)(ws + o);   o += al256((size_t)NE * 2);
    int* offs = (int*)(ws + o);           o += al256((size_t)(NN + 1) * 4);
    float* dinv = (float*)(ws + o);       o += al256((size_t)NN * 4);
    int* bcnt = (int*)(ws + o);           o += al256((size_t)NPB * 4);
    int* nodeord = (int*)(ws + o);        o += al256((size_t)NSLOT * 4);

    const int NB_GEMM = (NT + 3) / 4;     // 782
    const int NB_AGG = NSLOT / 16;        // 3136

    // preprocessing + layer-1 GEMM
    wconv_k<<<39, 256, 0, stream>>>(W1, W2, W3, W4, W1sw, W2sw, W3sw, W4sw, bcnt);
    mix_k<<<NBB + NB_GEMM, 256, 0, stream>>>(src, dst, bcnt, est, x, W1sw, Ha);
    fine_k<<<NPB, 1024, 0, stream>>>(est, bcnt, es, offs, dinv, nodeord);

    // fused layers: agg + bias + relu + next GEMM
    fused_k<<<NB_AGG, 192, 0, stream>>>(Ha, offs, es, dinv, b1, W2sw, nodeord, Hb);
    fused_k<<<NB_AGG, 192, 0, stream>>>(Hb, offs, es, dinv, b2, W3sw, nodeord, Ha);
    fused_k<<<NB_AGG, 192, 0, stream>>>(Ha, offs, es, dinv, b3, W4sw, nodeord, Hb);
    // final aggregation -> fp32 out
    aggf_k<<<NB_AGG, 192, 0, stream>>>(Hb, offs, es, dinv, b4, nodeord, out);
}

// Round 11
// 256.713 us; speedup vs baseline: 1.0662x; 1.0662x over previous
//
#include <hip/hip_runtime.h>
#include <hip/hip_fp16.h>

// GCN: 4 layers, N=50000, E=800000, C: 128->96->96->96->96
// Round-8 best-known structure (260us) + atile bank-conflict fix.
// - bucket sort by dst (bin + per-bucket in-LDS sort) -> es(ushort), offs,
//   dinv, nodeord (degree-sorted -> degree-uniform waves).
// - mix_k: bin blocks + layer-1 MFMA GEMM blocks in one dispatch.
// - fused_k (x3): gather-aggregate 16 nodes (+bias, relu) -> 3KB LDS A-tile
//   (rotate-swizzled rows: kills measured 12-way bank conflict on store) ->
//   MFMA with next layer's swizzled W -> row-major fp16 H.
// - aggf_k: final gather-aggregate + b4 -> fp32 out.
// - gather loop: 2-deep software pipeline (chunk=4) + serial tail (r10's
//   tail padding and r9's 3-stage pipeline both measured neutral/regression).
// - dinv[src] per edge (L2-hot; enorm precompute regressed r7).
// Regime (r10 counters): FETCH 73.5MB/layer = 8 XCD x 9.6MB H — compulsory
// cross-XCD L2 misses; 1.86 TB/s service, VALU 17%, Mfma 0.7% — latency-bound.

#define NN 50000
#define NE 800000
#define K1 128
#define CH 96
#define NT 3125    // NN/16 row-tiles (exact)
#define NPB 196    // dst buckets of 256 nodes
#define BCAP 5120  // slab capacity per bucket (mean 4082, ~16 sigma headroom)
#define NSLOT (NPB * 256)  // 50176 nodeord slots
#define NBB 782    // bin blocks (NE/1024 rounded up)

typedef _Float16 v8h __attribute__((ext_vector_type(8)));
typedef _Float16 v4h __attribute__((ext_vector_type(4)));
typedef float f4 __attribute__((ext_vector_type(4)));
typedef unsigned short ushort_t;

static inline size_t al256(size_t x) { return (x + 255) & ~size_t(255); }

// ---------------- weight swizzle + bcnt zero ----------------
__global__ __launch_bounds__(256) void wconv_k(const float* __restrict__ W1f,
                                               const float* __restrict__ W2f,
                                               const float* __restrict__ W3f,
                                               const float* __restrict__ W4f,
                                               _Float16* __restrict__ W1sw,
                                               _Float16* __restrict__ W2sw,
                                               _Float16* __restrict__ W3sw,
                                               _Float16* __restrict__ W4sw,
                                               int* __restrict__ bcnt) {
    int id = blockIdx.x * 256 + threadIdx.x;
    if (id < NPB) bcnt[id] = 0;
    const float* W;
    _Float16* Wsw;
    int K, lid;
    if (id < 3072) {            // 96*32
        W = W1f; Wsw = W1sw; K = K1; lid = id;
    } else {
        int r = id - 3072;
        if (r >= 3 * 2304) return;
        int wsel = r / 2304;
        lid = r % 2304;         // 96*24
        K = CH;
        W = (wsel == 0) ? W2f : (wsel == 1) ? W3f : W4f;
        Wsw = (wsel == 0) ? W2sw : (wsel == 1) ? W3sw : W4sw;
    }
    int kc = K / 4;
    int n = lid / kc, k0 = (lid % kc) * 4;
    v4h o;
    o.x = (_Float16)W[(k0 + 0) * 96 + n];
    o.y = (_Float16)W[(k0 + 1) * 96 + n];
    o.z = (_Float16)W[(k0 + 2) * 96 + n];
    o.w = (_Float16)W[(k0 + 3) * 96 + n];
    int off = (n >> 4) * (16 * K) + (k0 >> 3) * 128 + (n & 15) * 8 + (k0 & 7);
    *(v4h*)&Wsw[off] = o;
}

// ---------------- mix: bin (blocks [0,NBB)) + layer-1 GEMM (rest) ------------
__global__ __launch_bounds__(256) void mix_k(const int* __restrict__ src,
                                             const int* __restrict__ dst,
                                             int* __restrict__ bcnt,
                                             int* __restrict__ est,
                                             const float* __restrict__ Xf,
                                             const _Float16* __restrict__ Wsw,
                                             _Float16* __restrict__ Hh) {
    __shared__ _Float16 smem[64 * K1];  // 16KB; bin reuses first 1.6KB as ints
    int tid = threadIdx.x;

    if (blockIdx.x < NBB) {
        int* h2 = (int*)smem;
        int* basel = h2 + NPB;
        if (tid < NPB) h2[tid] = 0;
        __syncthreads();
        int base = blockIdx.x * 1024;
        int wv[4], bk[4], rk[4];
#pragma unroll
        for (int j = 0; j < 4; j++) {
            int i = base + j * 256 + tid;
            bk[j] = -1;
            if (i < NE) {
                int s = src[i], d = dst[i];
                bk[j] = d >> 8;
                rk[j] = atomicAdd(&h2[bk[j]], 1);
                wv[j] = s | ((d & 255) << 16);
            }
        }
        __syncthreads();
        if (tid < NPB && h2[tid]) basel[tid] = atomicAdd(&bcnt[tid], h2[tid]);
        __syncthreads();
#pragma unroll
        for (int j = 0; j < 4; j++) {
            if (bk[j] >= 0) est[bk[j] * BCAP + basel[bk[j]] + rk[j]] = wv[j];
        }
        return;
    }

    // ---- gemm1 path ----
    int bid = blockIdx.x - NBB;
    constexpr int K = K1;
    constexpr int KK = K / 32;
    int wave = tid >> 6;
    int lane = tid & 63;
    int l15 = lane & 15, quad = lane >> 4;
    int t = bid * 4 + wave;

    int row0 = bid * 64;
    for (int i = tid; i < 64 * (K / 4); i += 256) {
        int r = i / (K / 4), c = i % (K / 4);
        int gr = row0 + r;
        float4 v = make_float4(0.f, 0.f, 0.f, 0.f);
        if (gr < NN) v = *(const float4*)&Xf[(size_t)gr * K + c * 4];
        int k0 = c * 4;
        v4h h;
        h.x = (_Float16)v.x; h.y = (_Float16)v.y;
        h.z = (_Float16)v.z; h.w = (_Float16)v.w;
        int off = (r >> 4) * (16 * K) + (k0 >> 3) * 128 + (r & 15) * 8 + (k0 & 7);
        *(v4h*)&smem[off] = h;
    }
    __syncthreads();

    v8h a[KK];
#pragma unroll
    for (int kk = 0; kk < KK; kk++) {
        int off = wave * (16 * K) + (kk * 4 + quad) * 128 + l15 * 8;
        a[kk] = *(v8h*)&smem[off];
    }

    f4 acc[6];
#pragma unroll
    for (int cb = 0; cb < 6; cb++) acc[cb] = {0.f, 0.f, 0.f, 0.f};

#pragma unroll
    for (int kk = 0; kk < KK; kk++) {
        v8h b[6];
#pragma unroll
        for (int cb = 0; cb < 6; cb++)
            b[cb] = ((const v8h*)Wsw)[cb * (2 * K) + (kk * 4 + quad) * 16 + l15];
#pragma unroll
        for (int cb = 0; cb < 6; cb++)
            acc[cb] = __builtin_amdgcn_mfma_f32_16x16x32_f16(b[cb], a[kk], acc[cb], 0, 0, 0);
    }

    if (t < NT) {
        int row = t * 16 + l15;
#pragma unroll
        for (int cb = 0; cb < 6; cb++) {
            v4h o;
            o.x = (_Float16)acc[cb].x;
            o.y = (_Float16)acc[cb].y;
            o.z = (_Float16)acc[cb].z;
            o.w = (_Float16)acc[cb].w;
            *(v4h*)&Hh[(size_t)row * 96 + cb * 16 + quad * 4] = o;
        }
    }
}

// ---------------- per-bucket sort (1024 thr); emit es/offs/dinv/nodeord ------
__global__ __launch_bounds__(1024) void fine_k(const int* __restrict__ est,
                                               const int* __restrict__ bcnt,
                                               ushort_t* __restrict__ es,
                                               int* __restrict__ offs,
                                               float* __restrict__ dinv,
                                               int* __restrict__ nodeord) {
    __shared__ ushort_t lsrc[BCAP];
    __shared__ unsigned char ldst[BCAP];
    __shared__ ushort_t lout[BCAP];
    __shared__ int sc[256];
    __shared__ int hist[256];
    __shared__ int cur[256];
    __shared__ int dh[256];

    int b = blockIdx.x;
    int tid = threadIdx.x;
    bool lead = tid < 256;

    // global bucket prefix: scan bcnt[0..NPB)
    if (lead) sc[tid] = (tid < NPB) ? bcnt[tid] : 0;
    __syncthreads();
    for (int d = 1; d < 256; d <<= 1) {
        int t = 0;
        if (lead && tid >= d) t = sc[tid - d];
        __syncthreads();
        if (lead) sc[tid] += t;
        __syncthreads();
    }
    int cnt = bcnt[b];
    if (cnt > BCAP) cnt = BCAP;
    int base = sc[b] - cnt;  // exclusive prefix for this bucket

    if (lead) hist[tid] = 0;
    __syncthreads();
    for (int j = tid; j < cnt; j += 1024) {
        int w = est[b * BCAP + j];
        lsrc[j] = (ushort_t)(w & 0xFFFF);
        int l = (w >> 16) & 255;
        ldst[j] = (unsigned char)l;
        atomicAdd(&hist[l], 1);
    }
    __syncthreads();
    int hv = lead ? hist[tid] : 0;
    if (lead) sc[tid] = hv;
    __syncthreads();
    for (int d = 1; d < 256; d <<= 1) {
        int t = 0;
        if (lead && tid >= d) t = sc[tid - d];
        __syncthreads();
        if (lead) sc[tid] += t;
        __syncthreads();
    }
    int nvalid = NN - (b << 8);
    if (nvalid > 256) nvalid = 256;
    if (lead) {
        int excl = sc[tid] - hv;
        int n = (b << 8) + tid;
        if (tid < nvalid) {
            offs[n] = base + excl;
            dinv[n] = rsqrtf(1.0f + (float)hv);
        }
        if (n == NN) offs[NN] = base + excl;  // == NE (last bucket)
        cur[tid] = excl;
        dh[tid] = 0;
    }
    __syncthreads();
    for (int j = tid; j < cnt; j += 1024) {
        int r = atomicAdd(&cur[ldst[j]], 1);
        lout[r] = lsrc[j];
    }
    if (lead) {
        int dv = (hv > 255) ? 255 : hv;
        if (tid < nvalid) atomicAdd(&dh[dv], 1);
    }
    __syncthreads();
    for (int j = tid; j < cnt; j += 1024) es[base + j] = lout[j];
    // degree-rank counting sort -> nodeord
    int dhv = lead ? dh[tid] : 0;
    if (lead) sc[tid] = dhv;
    __syncthreads();
    for (int d = 1; d < 256; d <<= 1) {
        int t = 0;
        if (lead && tid >= d) t = sc[tid - d];
        __syncthreads();
        if (lead) sc[tid] += t;
        __syncthreads();
    }
    if (lead) cur[tid] = sc[tid] - dhv;
    __syncthreads();
    if (lead) {
        int dv = (hv > 255) ? 255 : hv;
        if (tid < nvalid) {
            int slot = atomicAdd(&cur[dv], 1);
            nodeord[b * 256 + slot] = (b << 8) + tid;
        } else {
            nodeord[b * 256 + tid] = b << 8;  // safe duplicate
        }
    }
}

// ---------------- shared gather-accumulate helper ----------------
__device__ __forceinline__ void acc8(v8h h, float w, float* a) {
    a[0] = fmaf(w, (float)h.s0, a[0]);
    a[1] = fmaf(w, (float)h.s1, a[1]);
    a[2] = fmaf(w, (float)h.s2, a[2]);
    a[3] = fmaf(w, (float)h.s3, a[3]);
    a[4] = fmaf(w, (float)h.s4, a[4]);
    a[5] = fmaf(w, (float)h.s5, a[5]);
    a[6] = fmaf(w, (float)h.s6, a[6]);
    a[7] = fmaf(w, (float)h.s7, a[7]);
}

// 2-deep software-pipelined gather (round-8 exact): chunk=4; next chunk's
// index+row loads issue before current chunk's FMAs.
__device__ __forceinline__ void gather_node(const _Float16* __restrict__ Hh,
                                            const int* __restrict__ offs,
                                            const ushort_t* __restrict__ es,
                                            const float* __restrict__ dinv,
                                            const float* __restrict__ bias,
                                            int n, int c8, float* a) {
    const _Float16* Hc = Hh + c8 * 8;
    float di = dinv[n];
    int e0 = offs[n], e1 = offs[n + 1];
    int e = e0;
    int nfull = (e1 - e0) >> 2;
    if (nfull > 0) {
        int s0[4];
        float w0[4];
        v8h h0[4];
#pragma unroll
        for (int j = 0; j < 4; j++) s0[j] = es[e + j];
#pragma unroll
        for (int j = 0; j < 4; j++) h0[j] = *(const v8h*)&Hc[(size_t)s0[j] * 96];
#pragma unroll
        for (int j = 0; j < 4; j++) w0[j] = dinv[s0[j]] * di;
        e += 4;
        for (int c = 1; c < nfull; c++) {
            int s1[4];
            float w1[4];
            v8h h1[4];
#pragma unroll
            for (int j = 0; j < 4; j++) s1[j] = es[e + j];
#pragma unroll
            for (int j = 0; j < 4; j++) h1[j] = *(const v8h*)&Hc[(size_t)s1[j] * 96];
#pragma unroll
            for (int j = 0; j < 4; j++) w1[j] = dinv[s1[j]] * di;
            // consume previous chunk while this chunk's loads are in flight
#pragma unroll
            for (int j = 0; j < 4; j++) acc8(h0[j], w0[j], a);
#pragma unroll
            for (int j = 0; j < 4; j++) {
                w0[j] = w1[j];
                h0[j] = h1[j];
            }
            e += 4;
        }
#pragma unroll
        for (int j = 0; j < 4; j++) acc8(h0[j], w0[j], a);
    }
    for (; e < e1; e++) {
        int s0 = es[e];
        float w0 = dinv[s0] * di;
        v8h h0 = *(const v8h*)&Hc[(size_t)s0 * 96];
        acc8(h0, w0, a);
    }
    // self-loop + bias
    v8h hs = *(const v8h*)&Hc[(size_t)n * 96];
    acc8(hs, di * di, a);
    float4 bv0 = *(const float4*)&bias[c8 * 8];
    float4 bv1 = *(const float4*)&bias[c8 * 8 + 4];
    a[0] += bv0.x; a[1] += bv0.y; a[2] += bv0.z; a[3] += bv0.w;
    a[4] += bv1.x; a[5] += bv1.y; a[6] += bv1.z; a[7] += bv1.w;
}

// ---------------- fused: F = relu(agg(Hprev)+bias); Hnext = F @ W ------------
// atile uses rotate-swizzled rows: element off = kblk*128 + ((row+kblk)&15)*8.
// Store side (row=g, kblk=c8) now spreads 12 c8-lanes across banks (was a
// measured 12-way conflict, SQ_LDS_BANK_CONFLICT=426k); load side stays 2-way.
__global__ __launch_bounds__(192) void fused_k(const _Float16* __restrict__ Hprev,
                                               const int* __restrict__ offs,
                                               const ushort_t* __restrict__ es,
                                               const float* __restrict__ dinv,
                                               const float* __restrict__ bias,
                                               const _Float16* __restrict__ Wsw,
                                               const int* __restrict__ nodeord,
                                               _Float16* __restrict__ Hnext) {
    __shared__ _Float16 atile[1536];  // 16 x 96 in MFMA-A swizzle (rotated)
    int tid = threadIdx.x;
    int g = tid / 12, c8 = tid % 12;
    int n = nodeord[blockIdx.x * 16 + g];
    float a[8] = {0.f, 0.f, 0.f, 0.f, 0.f, 0.f, 0.f, 0.f};
    gather_node(Hprev, offs, es, dinv, bias, n, c8, a);
    v8h o;
    o.s0 = (_Float16)fmaxf(a[0], 0.f); o.s1 = (_Float16)fmaxf(a[1], 0.f);
    o.s2 = (_Float16)fmaxf(a[2], 0.f); o.s3 = (_Float16)fmaxf(a[3], 0.f);
    o.s4 = (_Float16)fmaxf(a[4], 0.f); o.s5 = (_Float16)fmaxf(a[5], 0.f);
    o.s6 = (_Float16)fmaxf(a[6], 0.f); o.s7 = (_Float16)fmaxf(a[7], 0.f);
    *(v8h*)&atile[c8 * 128 + (((g + c8) & 15)) * 8] = o;
    __syncthreads();

    // MFMA phase: wave w handles col-blocks {2w, 2w+1}
    int wave = tid >> 6;
    int lane = tid & 63;
    int l15 = lane & 15, quad = lane >> 4;
    v8h af[3];
#pragma unroll
    for (int kk = 0; kk < 3; kk++) {
        int kblk = kk * 4 + quad;
        af[kk] = *(v8h*)&atile[kblk * 128 + (((l15 + kblk) & 15)) * 8];
    }
    int nrow = nodeord[blockIdx.x * 16 + l15];
#pragma unroll
    for (int c = 0; c < 2; c++) {
        int cb = wave * 2 + c;
        f4 acc = {0.f, 0.f, 0.f, 0.f};
#pragma unroll
        for (int kk = 0; kk < 3; kk++) {
            v8h bf = ((const v8h*)Wsw)[cb * 192 + (kk * 4 + quad) * 16 + l15];
            acc = __builtin_amdgcn_mfma_f32_16x16x32_f16(bf, af[kk], acc, 0, 0, 0);
        }
        v4h o2;
        o2.x = (_Float16)acc.x; o2.y = (_Float16)acc.y;
        o2.z = (_Float16)acc.z; o2.w = (_Float16)acc.w;
        *(v4h*)&Hnext[(size_t)nrow * 96 + cb * 16 + quad * 4] = o2;
    }
}

// ---------------- final aggregation -> fp32 out ----------------
__global__ __launch_bounds__(192) void aggf_k(const _Float16* __restrict__ Hh,
                                              const int* __restrict__ offs,
                                              const ushort_t* __restrict__ es,
                                              const float* __restrict__ dinv,
                                              const float* __restrict__ bias,
                                              const int* __restrict__ nodeord,
                                              float* __restrict__ out) {
    int tid = threadIdx.x;
    int g = tid / 12, c8 = tid % 12;
    int n = nodeord[blockIdx.x * 16 + g];
    float a[8] = {0.f, 0.f, 0.f, 0.f, 0.f, 0.f, 0.f, 0.f};
    gather_node(Hh, offs, es, dinv, bias, n, c8, a);
    float4 o0 = {a[0], a[1], a[2], a[3]};
    float4 o1 = {a[4], a[5], a[6], a[7]};
    *(float4*)&out[(size_t)n * 96 + c8 * 8] = o0;
    *(float4*)&out[(size_t)n * 96 + c8 * 8 + 4] = o1;
}

// ---------------- launch ----------------

extern "C" void kernel_launch(void* const* d_in, const int* in_sizes, int n_in,
                              void* d_out, int out_size, void* d_ws, size_t ws_size,
                              hipStream_t stream) {
    const float* x = (const float*)d_in[0];
    const int* ei = (const int*)d_in[1];
    const float* W1 = (const float*)d_in[2];
    const float* b1 = (const float*)d_in[3];
    const float* W2 = (const float*)d_in[4];
    const float* b2 = (const float*)d_in[5];
    const float* W3 = (const float*)d_in[6];
    const float* b3 = (const float*)d_in[7];
    const float* W4 = (const float*)d_in[8];
    const float* b4 = (const float*)d_in[9];
    float* out = (float*)d_out;

    const int* src = ei;
    const int* dst = ei + NE;

    char* ws = (char*)d_ws;
    size_t o = 0;
    _Float16* Ha = (_Float16*)(ws + o);   o += al256((size_t)NN * 96 * 2);
    _Float16* Hb = (_Float16*)(ws + o);   o += al256((size_t)NN * 96 * 2);
    _Float16* W1sw = (_Float16*)(ws + o); o += al256((size_t)96 * K1 * 2);
    _Float16* W2sw = (_Float16*)(ws + o); o += al256((size_t)96 * 96 * 2);
    _Float16* W3sw = (_Float16*)(ws + o); o += al256((size_t)96 * 96 * 2);
    _Float16* W4sw = (_Float16*)(ws + o); o += al256((size_t)96 * 96 * 2);
    int* est = (int*)(ws + o);            o += al256((size_t)NPB * BCAP * 4);
    ushort_t* es = (ushort_t*)(ws + o);   o += al256((size_t)NE * 2);
    int* offs = (int*)(ws + o);           o += al256((size_t)(NN + 1) * 4);
    float* dinv = (float*)(ws + o);       o += al256((size_t)NN * 4);
    int* bcnt = (int*)(ws + o);           o += al256((size_t)NPB * 4);
    int* nodeord = (int*)(ws + o);        o += al256((size_t)NSLOT * 4);

    const int NB_GEMM = (NT + 3) / 4;     // 782
    const int NB_AGG = NSLOT / 16;        // 3136

    // preprocessing + layer-1 GEMM
    wconv_k<<<39, 256, 0, stream>>>(W1, W2, W3, W4, W1sw, W2sw, W3sw, W4sw, bcnt);
    mix_k<<<NBB + NB_GEMM, 256, 0, stream>>>(src, dst, bcnt, est, x, W1sw, Ha);
    fine_k<<<NPB, 1024, 0, stream>>>(est, bcnt, es, offs, dinv, nodeord);

    // fused layers: agg + bias + relu + next GEMM
    fused_k<<<NB_AGG, 192, 0, stream>>>(Ha, offs, es, dinv, b1, W2sw, nodeord, Hb);
    fused_k<<<NB_AGG, 192, 0, stream>>>(Hb, offs, es, dinv, b2, W3sw, nodeord, Ha);
    fused_k<<<NB_AGG, 192, 0, stream>>>(Ha, offs, es, dinv, b3, W4sw, nodeord, Hb);
    // final aggregation -> fp32 out
    aggf_k<<<NB_AGG, 192, 0, stream>>>(Hb, offs, es, dinv, b4, nodeord, out);
}